// Round 2
// baseline (421.454 us; speedup 1.0000x reference)
//
#include <hip/hip_runtime.h>
#include <stdint.h>

// Performer (FAVOR+) attention, fused MFMA implementation for MI355X/gfx950.
//
// Per (b,h): ctx[m][e] = sum_n k'[n][m] v[n][e], s[m] = sum_n k'[n][m],
//            out[n][e] = (sum_m q'[n][m] ctx[m][e]) / (sum_m q'[n][m] s[m])
// with q'/k' = exp(x.P^T - 0.5|x|^2) + 1e-4  (ratio cancels -> dropped).
//
// R1 changes: T14 load/write-split staging (global->reg early, LDS write late),
// kside single barrier/iter w/ double-buffered tiles, qside ctx fragments in
// registers (LDS 86->49.5KB => 2 blocks/CU), den via per-wave slots (no atomics),
// qside grid 256->512, __launch_bounds__(512,4) to hold VGPR <= 128.

#define N_TOK 4096
#define DDIM  64
#define BHCNT 64
#define MFEAT 266
#define M2    272        // 17 tiles of 16 (features padded; pads masked to 0 on k-side)
#define QSTR  296        // q'/ctxT row stride in shorts
#define EPS_K 1e-4f

typedef float    f32x4 __attribute__((ext_vector_type(4)));
typedef _Float16 h8    __attribute__((ext_vector_type(8)));
typedef short    s8v   __attribute__((ext_vector_type(8)));
typedef short    s4v   __attribute__((ext_vector_type(4)));

static __device__ __forceinline__ short f2bf(float f) {
  uint32_t u = __float_as_uint(f);
  u = (u + 0x7fffu + ((u >> 16) & 1u)) >> 16;   // RNE
  return (short)u;
}
static __device__ __forceinline__ h8 ldh8(const char* p, int cb, int sw) {
  return *(const h8*)(p + (cb ^ sw));
}
static __device__ __forceinline__ s8v lds8(const char* p, int cb, int sw) {
  return *(const s8v*)(p + (cb ^ sw));
}
#define MFMA_F16(a, b, c)  __builtin_amdgcn_mfma_f32_16x16x32_f16((a), (b), (c), 0, 0, 0)
#define MFMA_BF16(a, b, c) __builtin_amdgcn_mfma_f32_16x16x32_bf16((a), (b), (c), 0, 0, 0)

// ---------------------------------------------------------------------------
// Kernel 1: K-side. 8 waves; wave owns m-tiles {wv, wv+8, (wv==0: 16)}.
// Pipeline per 64-row tile: WR(prev-loaded regs -> LDS dbuf) / barrier /
// LD(next tile -> regs) / features (f16 MFMA + exp -> kpT) / ctx (bf16 MFMA).
// ---------------------------------------------------------------------------
__global__ __launch_bounds__(512, 4) void perf_kside(
    const float* __restrict__ Kg, const float* __restrict__ Vg,
    const float* __restrict__ Pg, float* __restrict__ part_ctx,
    float* __restrict__ part_s, int nchunk, int rpc)
{
  __shared__ __attribute__((aligned(16))) short    kpT[M2 * 64];       // 34816 B; P staging first
  __shared__ __attribute__((aligned(16))) _Float16 klds[2][64 * 64];   // 16384 B
  __shared__ __attribute__((aligned(16))) short    vTl[2][64 * 64];    // 16384 B
  __shared__ float diag[2][64];                                        // 512 B

  const int tid  = threadIdx.x;
  const int lane = tid & 63;
  const int wv   = tid >> 6;
  const int l15  = lane & 15;
  const int g    = lane >> 4;
  const int bh   = blockIdx.x / nchunk;
  const int ch   = blockIdx.x % nchunk;

  const float* Kb = Kg + (size_t)bh * (N_TOK * DDIM) + (size_t)ch * rpc * DDIM;
  const float* Vb = Vg + (size_t)bh * (N_TOK * DDIM) + (size_t)ch * rpc * DDIM;

  // ---- stage P (fp32 -> f16, plain [272][64], zero pad rows) ----
  _Float16* Pl = (_Float16*)kpT;
  for (int slot = tid; slot < (M2 * DDIM) / 8; slot += 512) {
    int m = slot >> 3, d0 = (slot & 7) * 8;
    h8 v;
    if (m < MFEAT) {
      float4 a = *(const float4*)(Pg + m * DDIM + d0);
      float4 b = *(const float4*)(Pg + m * DDIM + d0 + 4);
      v[0] = (_Float16)a.x; v[1] = (_Float16)a.y; v[2] = (_Float16)a.z; v[3] = (_Float16)a.w;
      v[4] = (_Float16)b.x; v[5] = (_Float16)b.y; v[6] = (_Float16)b.z; v[7] = (_Float16)b.w;
    } else {
      #pragma unroll
      for (int j = 0; j < 8; ++j) v[j] = (_Float16)0.0f;
    }
    *(h8*)(Pl + slot * 8) = v;
  }
  __syncthreads();

  const int nmt = (wv == 0) ? 3 : 2;
  h8 pf[3][2];
  #pragma unroll
  for (int i = 0; i < 3; ++i) {
    int mt = (i == 2) ? 16 : (wv + 8 * i);
    int m  = mt * 16 + l15;
    #pragma unroll
    for (int km = 0; km < 2; ++km)
      pf[i][km] = *(const h8*)(Pl + m * DDIM + km * 32 + 8 * g);
  }
  __syncthreads();  // P region now reusable as kpT

  const f32x4 z4 = {0.f, 0.f, 0.f, 0.f};
  f32x4 acc[3][4];
  float sacc[3] = {0.f, 0.f, 0.f};
  #pragma unroll
  for (int i = 0; i < 3; ++i)
    #pragma unroll
    for (int e = 0; e < 4; ++e) acc[i][e] = z4;

  const int r  = tid >> 3;
  const int c8 = tid & 7;
  const int d0 = c8 * 8;
  const int iters = rpc >> 6;

  h8  kv8; s8v vv8; float ssv;

#define KS_LD(T)                                                              \
  {                                                                           \
    const float* kr_ = Kb + ((size_t)(T) * 64 + r) * DDIM + d0;               \
    float4 a_ = *(const float4*)kr_;                                          \
    float4 b_ = *(const float4*)(kr_ + 4);                                    \
    float ss_ = a_.x*a_.x + a_.y*a_.y + a_.z*a_.z + a_.w*a_.w                 \
              + b_.x*b_.x + b_.y*b_.y + b_.z*b_.z + b_.w*b_.w;                \
    ss_ += __shfl_xor(ss_, 1); ss_ += __shfl_xor(ss_, 2);                     \
    ss_ += __shfl_xor(ss_, 4);                                                \
    ssv = 0.5f * ss_;                                                         \
    kv8[0] = (_Float16)a_.x; kv8[1] = (_Float16)a_.y;                         \
    kv8[2] = (_Float16)a_.z; kv8[3] = (_Float16)a_.w;                         \
    kv8[4] = (_Float16)b_.x; kv8[5] = (_Float16)b_.y;                         \
    kv8[6] = (_Float16)b_.z; kv8[7] = (_Float16)b_.w;                         \
    const float* vr_ = Vb + ((size_t)(T) * 64 + r) * DDIM + d0;               \
    float4 c_ = *(const float4*)vr_;                                          \
    float4 e_ = *(const float4*)(vr_ + 4);                                    \
    vv8[0] = f2bf(c_.x); vv8[1] = f2bf(c_.y);                                 \
    vv8[2] = f2bf(c_.z); vv8[3] = f2bf(c_.w);                                 \
    vv8[4] = f2bf(e_.x); vv8[5] = f2bf(e_.y);                                 \
    vv8[6] = f2bf(e_.z); vv8[7] = f2bf(e_.w);                                 \
  }

#define KS_WR(B)                                                              \
  {                                                                           \
    if (c8 == 0) diag[B][r] = ssv;                                            \
    *(h8*)((char*)klds[B] + r * 128 + ((16 * c8) ^ ((r & 7) << 4))) = kv8;    \
    _Pragma("unroll")                                                         \
    for (int j_ = 0; j_ < 8; ++j_) {                                          \
      int e2_ = d0 + j_;                                                      \
      *(short*)((char*)vTl[B] + e2_ * 128 + ((2 * r) ^ ((e2_ & 7) << 4))) = vv8[j_]; \
    }                                                                         \
  }

  KS_LD(0);
  for (int it = 0; it < iters; ++it) {
    const int b = it & 1;
    KS_WR(b);
    __syncthreads();
    if (it + 1 < iters) KS_LD(it + 1);

    // ---- features: S = K.P^T, exp, write k'^T (wave-private rows) ----
    #pragma unroll
    for (int nt = 0; nt < 4; ++nt) {
      int n = nt * 16 + l15;
      const char* arow = (const char*)klds[b] + n * 128;
      int swn = (n & 7) << 4;
      h8 a0 = ldh8(arow, 16 * g, swn);
      h8 a1 = ldh8(arow, 64 + 16 * g, swn);
      float dg0 = diag[b][nt * 16 + 4 * g + 0];
      float dg1 = diag[b][nt * 16 + 4 * g + 1];
      float dg2 = diag[b][nt * 16 + 4 * g + 2];
      float dg3 = diag[b][nt * 16 + 4 * g + 3];
      #pragma unroll
      for (int i = 0; i < 3; ++i) {
        if (i >= nmt) continue;
        int mt = (i == 2) ? 16 : (wv + 8 * i);
        int m  = mt * 16 + l15;
        f32x4 sc = z4;
        sc = MFMA_F16(a0, pf[i][0], sc);
        sc = MFMA_F16(a1, pf[i][1], sc);
        float e0 = __expf(sc[0] - dg0) + EPS_K;
        float e1 = __expf(sc[1] - dg1) + EPS_K;
        float e2 = __expf(sc[2] - dg2) + EPS_K;
        float e3 = __expf(sc[3] - dg3) + EPS_K;
        if (m >= MFEAT) { e0 = 0.f; e1 = 0.f; e2 = 0.f; e3 = 0.f; }
        sacc[i] += (e0 + e1) + (e2 + e3);
        s4v kq; kq[0] = f2bf(e0); kq[1] = f2bf(e1); kq[2] = f2bf(e2); kq[3] = f2bf(e3);
        *(s4v*)((char*)kpT + m * 128 + ((32 * nt + 8 * g) ^ ((m & 7) << 4))) = kq;
      }
    }

    // ---- ctx_acc += k'^T . V (kpT rows wave-private; no barrier needed) ----
    #pragma unroll
    for (int i = 0; i < 3; ++i) {
      if (i >= nmt) continue;
      int mt = (i == 2) ? 16 : (wv + 8 * i);
      int m  = mt * 16 + l15;
      const char* arow = (const char*)kpT + m * 128;
      int swm = (m & 7) << 4;
      s8v A0 = lds8(arow, 16 * g, swm);
      s8v A1 = lds8(arow, 64 + 16 * g, swm);
      #pragma unroll
      for (int et = 0; et < 4; ++et) {
        int e = et * 16 + l15;
        const char* brow = (const char*)vTl[b] + e * 128;
        int swe = (e & 7) << 4;
        acc[i][et] = MFMA_BF16(A0, lds8(brow, 16 * g, swe), acc[i][et]);
        acc[i][et] = MFMA_BF16(A1, lds8(brow, 64 + 16 * g, swe), acc[i][et]);
      }
    }
  }

  // ---- store chunk partials ----
  float* pc = part_ctx + ((size_t)bh * nchunk + ch) * (M2 * DDIM);
  #pragma unroll
  for (int i = 0; i < 3; ++i) {
    if (i >= nmt) continue;
    int mt = (i == 2) ? 16 : (wv + 8 * i);
    #pragma unroll
    for (int et = 0; et < 4; ++et) {
      #pragma unroll
      for (int rr = 0; rr < 4; ++rr) {
        int m = mt * 16 + 4 * g + rr;
        pc[m * DDIM + et * 16 + l15] = acc[i][et][rr];
      }
    }
  }
  float* ps = part_s + ((size_t)bh * nchunk + ch) * M2;
  #pragma unroll
  for (int i = 0; i < 3; ++i) {
    if (i >= nmt) continue;
    int mt = (i == 2) ? 16 : (wv + 8 * i);
    float v = sacc[i];
    v += __shfl_xor(v, 16);
    v += __shfl_xor(v, 32);
    if (lane < 16) ps[mt * 16 + lane] = v;
  }
}

// ---------------------------------------------------------------------------
// Kernel 2: reduce chunk partials -> final ctx [bh][272][64] and s [bh][272].
// ---------------------------------------------------------------------------
__global__ void perf_reduce(const float* __restrict__ part_ctx,
                            const float* __restrict__ part_s,
                            float* __restrict__ ctxg, float* __restrict__ sveca,
                            int nchunk)
{
  int idx = blockIdx.x * 256 + threadIdx.x;
  const int tot_c = BHCNT * M2 * DDIM;
  if (idx < tot_c) {
    int bh = idx / (M2 * DDIM);
    int me = idx - bh * (M2 * DDIM);
    float s = 0.f;
    for (int c = 0; c < nchunk; ++c)
      s += part_ctx[((size_t)bh * nchunk + c) * (M2 * DDIM) + me];
    ctxg[idx] = s;
  } else {
    int j = idx - tot_c;
    if (j < BHCNT * M2) {
      int bh = j / M2;
      int m  = j - bh * M2;
      float s = 0.f;
      for (int c = 0; c < nchunk; ++c)
        s += part_s[((size_t)bh * nchunk + c) * M2 + m];
      sveca[j] = s;
    }
  }
}

// ---------------------------------------------------------------------------
// Kernel 3: Q-side. ctx^T fragments held in per-wave REGISTERS (loaded once
// via LDS bounce). LDS = q' [64][296] + ql + s_l + den_w + dia = 49.5 KB
// -> 2 blocks/CU. Out phase: wave = (e-tile wv&3, n-half wv>>2).
// ---------------------------------------------------------------------------
__global__ __launch_bounds__(512, 4) void perf_qside(
    const float* __restrict__ Qg, const float* __restrict__ Pg,
    const float* __restrict__ ctxg, const float* __restrict__ sveca,
    float* __restrict__ Og)
{
  __shared__ __attribute__((aligned(16))) short    qp[64 * QSTR];   // 37888 B; P then ctxT then q'
  __shared__ __attribute__((aligned(16))) _Float16 ql[64 * 64];     // 8192 B, swizzled
  __shared__ float s_l[M2];                                         // 1088 B
  __shared__ float den_w[64 * 8];                                   // 2048 B per-wave den partials
  __shared__ float dia[64];                                         // 256 B

  const int tid  = threadIdx.x;
  const int lane = tid & 63;
  const int wv   = tid >> 6;
  const int l15  = lane & 15;
  const int g    = lane >> 4;
  const int bh   = blockIdx.x >> 3;
  const int ch   = blockIdx.x & 7;

  const float* Qb = Qg + (size_t)bh * (N_TOK * DDIM) + (size_t)ch * 512 * DDIM;
  float*       Ob = Og + (size_t)bh * (N_TOK * DDIM) + (size_t)ch * 512 * DDIM;

  // ---- stage P (f16 [272][64]) into q' region ----
  _Float16* Pl = (_Float16*)qp;
  for (int slot = tid; slot < (M2 * DDIM) / 8; slot += 512) {
    int m = slot >> 3, d0 = (slot & 7) * 8;
    h8 v;
    if (m < MFEAT) {
      float4 a = *(const float4*)(Pg + m * DDIM + d0);
      float4 b = *(const float4*)(Pg + m * DDIM + d0 + 4);
      v[0] = (_Float16)a.x; v[1] = (_Float16)a.y; v[2] = (_Float16)a.z; v[3] = (_Float16)a.w;
      v[4] = (_Float16)b.x; v[5] = (_Float16)b.y; v[6] = (_Float16)b.z; v[7] = (_Float16)b.w;
    } else {
      #pragma unroll
      for (int j = 0; j < 8; ++j) v[j] = (_Float16)0.0f;
    }
    *(h8*)(Pl + slot * 8) = v;
  }
  __syncthreads();

  const int nmt = (wv == 0) ? 3 : 2;
  h8 pf[3][2];
  #pragma unroll
  for (int i = 0; i < 3; ++i) {
    int mt = (i == 2) ? 16 : (wv + 8 * i);
    int m  = mt * 16 + l15;
    #pragma unroll
    for (int km = 0; km < 2; ++km)
      pf[i][km] = *(const h8*)(Pl + m * DDIM + km * 32 + 8 * g);
  }
  __syncthreads();  // P region now reusable

  // ---- stage ctx^T into qp as [64][296] bf16 (coalesced global reads) ----
  const float* cbp = ctxg + (size_t)bh * (M2 * DDIM);
  for (int slot = tid; slot < M2 * DDIM; slot += 512) {
    int m = slot >> 6, e = slot & 63;
    qp[e * QSTR + m] = f2bf(cbp[slot]);
  }
  for (int idx = tid; idx < 64 * 24; idx += 512) {     // zero ctxT pad cols 272..295
    int e = idx / 24, m = 272 + idx % 24;
    qp[e * QSTR + m] = 0;
  }
  for (int m = tid; m < M2; m += 512) s_l[m] = sveca[bh * M2 + m];
  __syncthreads();

  // ---- ctx fragments -> registers (wave's e-tile = wv&3) ----
  const int et = wv & 3, nh = wv >> 2;
  s8v cf[9];
  #pragma unroll
  for (int ks = 0; ks < 9; ++ks)
    cf[ks] = *(const s8v*)((const char*)(qp + (et * 16 + l15) * QSTR) + ks * 64 + 16 * g);
  __syncthreads();

  // ---- zero q' stale pad cols 272..287 (cols >271 never rewritten) ----
  for (int idx = tid; idx < 64 * 16; idx += 512) {
    int rr = idx >> 4, cc = 272 + (idx & 15);
    qp[rr * QSTR + cc] = 0;
  }

  const f32x4 z4 = {0.f, 0.f, 0.f, 0.f};
  const int r  = tid >> 3;
  const int c8 = tid & 7;
  const int d0 = c8 * 8;
  h8 qv8; float ssq;

#define QS_LD(T)                                                              \
  {                                                                           \
    const float* qr_ = Qb + ((size_t)(T) * 64 + r) * DDIM + d0;               \
    float4 a_ = *(const float4*)qr_;                                          \
    float4 b_ = *(const float4*)(qr_ + 4);                                    \
    float ss_ = a_.x*a_.x + a_.y*a_.y + a_.z*a_.z + a_.w*a_.w                 \
              + b_.x*b_.x + b_.y*b_.y + b_.z*b_.z + b_.w*b_.w;                \
    ss_ += __shfl_xor(ss_, 1); ss_ += __shfl_xor(ss_, 2);                     \
    ss_ += __shfl_xor(ss_, 4);                                                \
    ssq = 0.5f * ss_;                                                         \
    qv8[0] = (_Float16)a_.x; qv8[1] = (_Float16)a_.y;                         \
    qv8[2] = (_Float16)a_.z; qv8[3] = (_Float16)a_.w;                         \
    qv8[4] = (_Float16)b_.x; qv8[5] = (_Float16)b_.y;                         \
    qv8[6] = (_Float16)b_.z; qv8[7] = (_Float16)b_.w;                         \
  }

#define QS_WR()                                                               \
  {                                                                           \
    if (c8 == 0) dia[r] = ssq;                                                \
    *(h8*)((char*)ql + r * 128 + ((16 * c8) ^ ((r & 7) << 4))) = qv8;         \
  }

  QS_LD(0);
  for (int it = 0; it < 8; ++it) {
    QS_WR();
    __syncthreads();   // ql/dia ready; also fences q'/den_w WAR vs prev out
    if (it + 1 < 8) QS_LD(it + 1);

    // ---- features: S = Q.P^T, exp, q' column writes, den partials ----
    #pragma unroll
    for (int nt = 0; nt < 4; ++nt) {
      int n = nt * 16 + l15;
      const char* arow = (const char*)ql + n * 128;
      int swn = (n & 7) << 4;
      h8 a0 = ldh8(arow, 16 * g, swn);
      h8 a1 = ldh8(arow, 64 + 16 * g, swn);
      float dg0 = dia[nt * 16 + 4 * g + 0];
      float dg1 = dia[nt * 16 + 4 * g + 1];
      float dg2 = dia[nt * 16 + 4 * g + 2];
      float dg3 = dia[nt * 16 + 4 * g + 3];
      float dl0 = 0.f, dl1 = 0.f, dl2 = 0.f, dl3 = 0.f;
      #pragma unroll
      for (int i = 0; i < 3; ++i) {
        if (i >= nmt) continue;
        int mt = (i == 2) ? 16 : (wv + 8 * i);
        int m  = mt * 16 + l15;
        f32x4 sc = z4;
        sc = MFMA_F16(a0, pf[i][0], sc);
        sc = MFMA_F16(a1, pf[i][1], sc);
        float sm = s_l[m];
        float e0 = __expf(sc[0] - dg0) + EPS_K;
        float e1 = __expf(sc[1] - dg1) + EPS_K;
        float e2 = __expf(sc[2] - dg2) + EPS_K;
        float e3 = __expf(sc[3] - dg3) + EPS_K;
        short* qcol = qp + m;
        qcol[(nt * 16 + 4 * g + 0) * QSTR] = f2bf(e0);
        qcol[(nt * 16 + 4 * g + 1) * QSTR] = f2bf(e1);
        qcol[(nt * 16 + 4 * g + 2) * QSTR] = f2bf(e2);
        qcol[(nt * 16 + 4 * g + 3) * QSTR] = f2bf(e3);
        dl0 += e0 * sm; dl1 += e1 * sm; dl2 += e2 * sm; dl3 += e3 * sm;
      }
      dl0 += __shfl_xor(dl0, 1); dl0 += __shfl_xor(dl0, 2); dl0 += __shfl_xor(dl0, 4); dl0 += __shfl_xor(dl0, 8);
      dl1 += __shfl_xor(dl1, 1); dl1 += __shfl_xor(dl1, 2); dl1 += __shfl_xor(dl1, 4); dl1 += __shfl_xor(dl1, 8);
      dl2 += __shfl_xor(dl2, 1); dl2 += __shfl_xor(dl2, 2); dl2 += __shfl_xor(dl2, 4); dl2 += __shfl_xor(dl2, 8);
      dl3 += __shfl_xor(dl3, 1); dl3 += __shfl_xor(dl3, 2); dl3 += __shfl_xor(dl3, 4); dl3 += __shfl_xor(dl3, 8);
      if (l15 == 0) {
        den_w[(nt * 16 + 4 * g + 0) * 8 + wv] = dl0;
        den_w[(nt * 16 + 4 * g + 1) * 8 + wv] = dl1;
        den_w[(nt * 16 + 4 * g + 2) * 8 + wv] = dl2;
        den_w[(nt * 16 + 4 * g + 3) * 8 + wv] = dl3;
      }
    }
    __syncthreads();

    // ---- out: wave (et, nh) computes 2 n-tiles x 1 e-tile ----
    #pragma unroll
    for (int nt2 = 0; nt2 < 2; ++nt2) {
      int nt = nh * 2 + nt2;
      const char* arow = (const char*)(qp + (nt * 16 + l15) * QSTR);
      f32x4 o = z4;
      #pragma unroll
      for (int ks = 0; ks < 9; ++ks) {
        s8v A = *(const s8v*)(arow + ks * 64 + 16 * g);
        o = MFMA_BF16(A, cf[ks], o);
      }
      #pragma unroll
      for (int rr = 0; rr < 4; ++rr) {
        int n = nt * 16 + 4 * g + rr;
        const f32x4* dq = (const f32x4*)(den_w + n * 8);
        f32x4 x = dq[0], y = dq[1];
        float s = ((x[0] + x[1]) + (x[2] + x[3])) + ((y[0] + y[1]) + (y[2] + y[3]));
        float dv = __builtin_amdgcn_rcpf(s);
        Ob[((size_t)it * 64 + n) * DDIM + et * 16 + l15] = o[rr] * dv;
      }
    }
  }
}

// ---------------------------------------------------------------------------
extern "C" void kernel_launch(void* const* d_in, const int* in_sizes, int n_in,
                              void* d_out, int out_size, void* d_ws, size_t ws_size,
                              hipStream_t stream)
{
  const float* q = (const float*)d_in[0];
  const float* k = (const float*)d_in[1];
  const float* v = (const float*)d_in[2];
  const float* p = (const float*)d_in[3];
  float* out = (float*)d_out;
  (void)in_sizes; (void)n_in; (void)out_size;

  // ws: [part_ctx BH*nch*272*64][part_s BH*nch*272][ctx BH*272*64][s BH*272] (fp32)
  int nch = 8;
  while (nch > 1) {
    size_t need = (size_t)4 * ((size_t)BHCNT * nch * (M2 * DDIM) + (size_t)BHCNT * nch * M2
                               + (size_t)BHCNT * (M2 * DDIM) + (size_t)BHCNT * M2);
    if (need <= ws_size) break;
    nch >>= 1;
  }
  float* part_ctx = (float*)d_ws;
  float* part_s   = part_ctx + (size_t)BHCNT * nch * (M2 * DDIM);
  float* ctxg     = part_s   + (size_t)BHCNT * nch * M2;
  float* sveca    = ctxg     + (size_t)BHCNT * (M2 * DDIM);

  perf_kside<<<dim3(BHCNT * nch), dim3(512), 0, stream>>>(k, v, p, part_ctx, part_s,
                                                          nch, N_TOK / nch);
  int redn = (BHCNT * M2 * DDIM + BHCNT * M2 + 255) / 256;
  perf_reduce<<<dim3(redn), dim3(256), 0, stream>>>(part_ctx, part_s, ctxg, sveca, nch);
  perf_qside<<<dim3(BHCNT * 8), dim3(512), 0, stream>>>(q, p, ctxg, sveca, out);
}

// Round 3
// 387.813 us; speedup vs baseline: 1.0867x; 1.0867x over previous
//
#include <hip/hip_runtime.h>
#include <stdint.h>

// Performer (FAVOR+) attention, fused MFMA implementation for MI355X/gfx950.
//
// Per (b,h): ctx[m][e] = sum_n k'[n][m] v[n][e], s[m] = sum_n k'[n][m],
//            out[n][e] = (sum_m q'[n][m] ctx[m][e]) / (sum_m q'[n][m] s[m])
// with q'/k' = exp(x.P^T - 0.5|x|^2) + 1e-4  (ratio cancels -> dropped).
//
// R3: fix R2's register-spill regression (VGPR cap 128 at 2 blocks/CU).
// Every wave owns exactly 2 m-tiles (acc 48->36, pf 24->16+8). The 17th
// m-tile (m=256..271): features round-robin (wave nt handles n-tile nt,
// reading P16 from a persistent 2KB LDS copy), ctx split by e-tile over
// waves 0-3. One extra barrier/iter (tile-16 kpT rows cross waves).

#define N_TOK 4096
#define DDIM  64
#define BHCNT 64
#define MFEAT 266
#define M2    272        // 17 tiles of 16 (pads masked to 0 on k-side)
#define QSTR  296        // q'/ctxT row stride in shorts
#define EPS_K 1e-4f

typedef float    f32x4 __attribute__((ext_vector_type(4)));
typedef _Float16 h8    __attribute__((ext_vector_type(8)));
typedef short    s8v   __attribute__((ext_vector_type(8)));
typedef short    s4v   __attribute__((ext_vector_type(4)));

static __device__ __forceinline__ short f2bf(float f) {
  uint32_t u = __float_as_uint(f);
  u = (u + 0x7fffu + ((u >> 16) & 1u)) >> 16;   // RNE
  return (short)u;
}
static __device__ __forceinline__ h8 ldh8(const char* p, int cb, int sw) {
  return *(const h8*)(p + (cb ^ sw));
}
static __device__ __forceinline__ s8v lds8(const char* p, int cb, int sw) {
  return *(const s8v*)(p + (cb ^ sw));
}
#define MFMA_F16(a, b, c)  __builtin_amdgcn_mfma_f32_16x16x32_f16((a), (b), (c), 0, 0, 0)
#define MFMA_BF16(a, b, c) __builtin_amdgcn_mfma_f32_16x16x32_bf16((a), (b), (c), 0, 0, 0)

// ---------------------------------------------------------------------------
// Kernel 1: K-side. 8 waves; wave owns m-tiles {wv, wv+8}; tile 16 shared.
// Pipeline per 64-row tile: WR(regs->LDS dbuf) / bar / LD(next->regs) /
// features (f16 MFMA + exp -> kpT) / bar / ctx (bf16 MFMA).
// ---------------------------------------------------------------------------
__global__ __launch_bounds__(512, 4) void perf_kside(
    const float* __restrict__ Kg, const float* __restrict__ Vg,
    const float* __restrict__ Pg, float* __restrict__ part_ctx,
    float* __restrict__ part_s, int nchunk, int rpc)
{
  __shared__ __attribute__((aligned(16))) short    kpT[M2 * 64];       // 34816 B; P staging first
  __shared__ __attribute__((aligned(16))) _Float16 klds[2][64 * 64];   // 16384 B
  __shared__ __attribute__((aligned(16))) short    vTl[2][64 * 64];    // 16384 B
  __shared__ __attribute__((aligned(16))) _Float16 P16[16 * 64];       // 2048 B, persistent
  __shared__ float diag[2][64];
  __shared__ float s16buf[64];

  const int tid  = threadIdx.x;
  const int lane = tid & 63;
  const int wv   = tid >> 6;
  const int l15  = lane & 15;
  const int g    = lane >> 4;
  const int bh   = blockIdx.x / nchunk;
  const int ch   = blockIdx.x % nchunk;

  const float* Kb = Kg + (size_t)bh * (N_TOK * DDIM) + (size_t)ch * rpc * DDIM;
  const float* Vb = Vg + (size_t)bh * (N_TOK * DDIM) + (size_t)ch * rpc * DDIM;

  // ---- stage P (fp32 -> f16, plain [272][64], zero pad rows; tile16 copy) ----
  _Float16* Pl = (_Float16*)kpT;
  for (int slot = tid; slot < (M2 * DDIM) / 8; slot += 512) {
    int m = slot >> 3, d0 = (slot & 7) * 8;
    h8 v;
    if (m < MFEAT) {
      float4 a = *(const float4*)(Pg + m * DDIM + d0);
      float4 b = *(const float4*)(Pg + m * DDIM + d0 + 4);
      v[0] = (_Float16)a.x; v[1] = (_Float16)a.y; v[2] = (_Float16)a.z; v[3] = (_Float16)a.w;
      v[4] = (_Float16)b.x; v[5] = (_Float16)b.y; v[6] = (_Float16)b.z; v[7] = (_Float16)b.w;
    } else {
      #pragma unroll
      for (int j = 0; j < 8; ++j) v[j] = (_Float16)0.0f;
    }
    *(h8*)(Pl + slot * 8) = v;
    if (m >= 256) *(h8*)(P16 + (m - 256) * DDIM + d0) = v;
  }
  __syncthreads();

  h8 pf[2][2];
  #pragma unroll
  for (int i = 0; i < 2; ++i) {
    int m = (wv + 8 * i) * 16 + l15;
    #pragma unroll
    for (int km = 0; km < 2; ++km)
      pf[i][km] = *(const h8*)(Pl + m * DDIM + km * 32 + 8 * g);
  }
  h8 pf16[2];
  #pragma unroll
  for (int km = 0; km < 2; ++km)
    pf16[km] = *(const h8*)(P16 + l15 * DDIM + km * 32 + 8 * g);
  __syncthreads();  // P region now reusable as kpT

  const f32x4 z4 = {0.f, 0.f, 0.f, 0.f};
  f32x4 acc[2][4], acc16 = z4;
  float sacc[2] = {0.f, 0.f}, sacc16 = 0.f;
  #pragma unroll
  for (int i = 0; i < 2; ++i)
    #pragma unroll
    for (int e = 0; e < 4; ++e) acc[i][e] = z4;

  const int r  = tid >> 3;
  const int c8 = tid & 7;
  const int d0 = c8 * 8;
  const int iters = rpc >> 6;

  h8  kv8; s8v vv8; float ssv;

#define KS_LD(T)                                                              \
  {                                                                           \
    const float* kr_ = Kb + ((size_t)(T) * 64 + r) * DDIM + d0;               \
    float4 a_ = *(const float4*)kr_;                                          \
    float4 b_ = *(const float4*)(kr_ + 4);                                    \
    float ss_ = a_.x*a_.x + a_.y*a_.y + a_.z*a_.z + a_.w*a_.w                 \
              + b_.x*b_.x + b_.y*b_.y + b_.z*b_.z + b_.w*b_.w;                \
    ss_ += __shfl_xor(ss_, 1); ss_ += __shfl_xor(ss_, 2);                     \
    ss_ += __shfl_xor(ss_, 4);                                                \
    ssv = 0.5f * ss_;                                                         \
    kv8[0] = (_Float16)a_.x; kv8[1] = (_Float16)a_.y;                         \
    kv8[2] = (_Float16)a_.z; kv8[3] = (_Float16)a_.w;                         \
    kv8[4] = (_Float16)b_.x; kv8[5] = (_Float16)b_.y;                         \
    kv8[6] = (_Float16)b_.z; kv8[7] = (_Float16)b_.w;                         \
    const float* vr_ = Vb + ((size_t)(T) * 64 + r) * DDIM + d0;               \
    float4 c_ = *(const float4*)vr_;                                          \
    float4 e_ = *(const float4*)(vr_ + 4);                                    \
    vv8[0] = f2bf(c_.x); vv8[1] = f2bf(c_.y);                                 \
    vv8[2] = f2bf(c_.z); vv8[3] = f2bf(c_.w);                                 \
    vv8[4] = f2bf(e_.x); vv8[5] = f2bf(e_.y);                                 \
    vv8[6] = f2bf(e_.z); vv8[7] = f2bf(e_.w);                                 \
  }

#define KS_WR(B)                                                              \
  {                                                                           \
    if (c8 == 0) diag[B][r] = ssv;                                            \
    *(h8*)((char*)klds[B] + r * 128 + ((16 * c8) ^ ((r & 7) << 4))) = kv8;    \
    _Pragma("unroll")                                                         \
    for (int j_ = 0; j_ < 8; ++j_) {                                          \
      int e2_ = d0 + j_;                                                      \
      *(short*)((char*)vTl[B] + e2_ * 128 + ((2 * r) ^ ((e2_ & 7) << 4))) = vv8[j_]; \
    }                                                                         \
  }

  KS_LD(0);
  for (int it = 0; it < iters; ++it) {
    const int b = it & 1;
    KS_WR(b);
    __syncthreads();
    if (it + 1 < iters) KS_LD(it + 1);

    // ---- features: S = K.P^T, exp, write k'^T ----
    #pragma unroll
    for (int nt = 0; nt < 4; ++nt) {
      int n = nt * 16 + l15;
      const char* arow = (const char*)klds[b] + n * 128;
      int swn = (n & 7) << 4;
      h8 a0 = ldh8(arow, 16 * g, swn);
      h8 a1 = ldh8(arow, 64 + 16 * g, swn);
      float dg0 = diag[b][nt * 16 + 4 * g + 0];
      float dg1 = diag[b][nt * 16 + 4 * g + 1];
      float dg2 = diag[b][nt * 16 + 4 * g + 2];
      float dg3 = diag[b][nt * 16 + 4 * g + 3];
      #pragma unroll
      for (int i = 0; i < 2; ++i) {
        int m = (wv + 8 * i) * 16 + l15;              // m <= 255 < 266: no mask
        f32x4 sc = z4;
        sc = MFMA_F16(a0, pf[i][0], sc);
        sc = MFMA_F16(a1, pf[i][1], sc);
        float e0 = __expf(sc[0] - dg0) + EPS_K;
        float e1 = __expf(sc[1] - dg1) + EPS_K;
        float e2 = __expf(sc[2] - dg2) + EPS_K;
        float e3 = __expf(sc[3] - dg3) + EPS_K;
        sacc[i] += (e0 + e1) + (e2 + e3);
        s4v kq; kq[0] = f2bf(e0); kq[1] = f2bf(e1); kq[2] = f2bf(e2); kq[3] = f2bf(e3);
        *(s4v*)((char*)kpT + m * 128 + ((32 * nt + 8 * g) ^ ((m & 7) << 4))) = kq;
      }
      if (wv == nt) {                                  // tile 16 features (round-robin)
        int m = 256 + l15;
        f32x4 sc = z4;
        sc = MFMA_F16(a0, pf16[0], sc);
        sc = MFMA_F16(a1, pf16[1], sc);
        float e0 = __expf(sc[0] - dg0) + EPS_K;
        float e1 = __expf(sc[1] - dg1) + EPS_K;
        float e2 = __expf(sc[2] - dg2) + EPS_K;
        float e3 = __expf(sc[3] - dg3) + EPS_K;
        if (l15 >= 10) { e0 = 0.f; e1 = 0.f; e2 = 0.f; e3 = 0.f; }  // m >= 266
        sacc16 += (e0 + e1) + (e2 + e3);
        s4v kq; kq[0] = f2bf(e0); kq[1] = f2bf(e1); kq[2] = f2bf(e2); kq[3] = f2bf(e3);
        *(s4v*)((char*)kpT + m * 128 + ((32 * nt + 8 * g) ^ ((m & 7) << 4))) = kq;
      }
    }
    __syncthreads();   // tile-16 kpT rows cross waves

    // ---- ctx_acc += k'^T . V ----
    #pragma unroll
    for (int i = 0; i < 2; ++i) {
      int m = (wv + 8 * i) * 16 + l15;
      const char* arow = (const char*)kpT + m * 128;
      int swm = (m & 7) << 4;
      s8v A0 = lds8(arow, 16 * g, swm);
      s8v A1 = lds8(arow, 64 + 16 * g, swm);
      #pragma unroll
      for (int et = 0; et < 4; ++et) {
        int e = et * 16 + l15;
        const char* brow = (const char*)vTl[b] + e * 128;
        int swe = (e & 7) << 4;
        acc[i][et] = MFMA_BF16(A0, lds8(brow, 16 * g, swe), acc[i][et]);
        acc[i][et] = MFMA_BF16(A1, lds8(brow, 64 + 16 * g, swe), acc[i][et]);
      }
    }
    if (wv < 4) {                                      // tile-16 ctx: e-tile = wv
      int m = 256 + l15;
      const char* arow = (const char*)kpT + m * 128;
      int swm = (m & 7) << 4;
      s8v A0 = lds8(arow, 16 * g, swm);
      s8v A1 = lds8(arow, 64 + 16 * g, swm);
      int e = wv * 16 + l15;
      const char* brow = (const char*)vTl[b] + e * 128;
      int swe = (e & 7) << 4;
      acc16 = MFMA_BF16(A0, lds8(brow, 16 * g, swe), acc16);
      acc16 = MFMA_BF16(A1, lds8(brow, 64 + 16 * g, swe), acc16);
    }
  }

  // ---- store chunk partials ----
  float* pc = part_ctx + ((size_t)bh * nchunk + ch) * (M2 * DDIM);
  #pragma unroll
  for (int i = 0; i < 2; ++i) {
    int mt = wv + 8 * i;
    #pragma unroll
    for (int et = 0; et < 4; ++et)
      #pragma unroll
      for (int rr = 0; rr < 4; ++rr)
        pc[(mt * 16 + 4 * g + rr) * DDIM + et * 16 + l15] = acc[i][et][rr];
  }
  if (wv < 4) {
    #pragma unroll
    for (int rr = 0; rr < 4; ++rr)
      pc[(256 + 4 * g + rr) * DDIM + wv * 16 + l15] = acc16[rr];
  }
  float* ps = part_s + ((size_t)bh * nchunk + ch) * M2;
  #pragma unroll
  for (int i = 0; i < 2; ++i) {
    float v = sacc[i];
    v += __shfl_xor(v, 16);
    v += __shfl_xor(v, 32);
    if (lane < 16) ps[(wv + 8 * i) * 16 + lane] = v;
  }
  if (wv < 4) {
    float v = sacc16;
    v += __shfl_xor(v, 16);
    v += __shfl_xor(v, 32);
    if (lane < 16) s16buf[wv * 16 + lane] = v;
  }
  __syncthreads();
  if (tid < 16)
    ps[256 + tid] = (s16buf[tid] + s16buf[16 + tid]) + (s16buf[32 + tid] + s16buf[48 + tid]);
}

// ---------------------------------------------------------------------------
// Kernel 2: reduce chunk partials -> final ctx [bh][272][64] and s [bh][272].
// ---------------------------------------------------------------------------
__global__ void perf_reduce(const float* __restrict__ part_ctx,
                            const float* __restrict__ part_s,
                            float* __restrict__ ctxg, float* __restrict__ sveca,
                            int nchunk)
{
  int idx = blockIdx.x * 256 + threadIdx.x;
  const int tot_c = BHCNT * M2 * DDIM;
  if (idx < tot_c) {
    int bh = idx / (M2 * DDIM);
    int me = idx - bh * (M2 * DDIM);
    float s = 0.f;
    for (int c = 0; c < nchunk; ++c)
      s += part_ctx[((size_t)bh * nchunk + c) * (M2 * DDIM) + me];
    ctxg[idx] = s;
  } else {
    int j = idx - tot_c;
    if (j < BHCNT * M2) {
      int bh = j / M2;
      int m  = j - bh * M2;
      float s = 0.f;
      for (int c = 0; c < nchunk; ++c)
        s += part_s[((size_t)bh * nchunk + c) * M2 + m];
      sveca[j] = s;
    }
  }
}

// ---------------------------------------------------------------------------
// Kernel 3: Q-side. ctx^T fragments in per-wave registers (LDS bounce).
// LDS ~50 KB -> 2 blocks/CU. Wave owns m-tiles {wv, wv+8}; tile 16
// round-robin (wave nt, P16 from LDS). Out: wave = (e-tile wv&3, n-half).
// ---------------------------------------------------------------------------
__global__ __launch_bounds__(512, 4) void perf_qside(
    const float* __restrict__ Qg, const float* __restrict__ Pg,
    const float* __restrict__ ctxg, const float* __restrict__ sveca,
    float* __restrict__ Og)
{
  __shared__ __attribute__((aligned(16))) short    qp[64 * QSTR];   // 37888 B; P then ctxT then q'
  __shared__ __attribute__((aligned(16))) _Float16 ql[64 * 64];     // 8192 B, swizzled
  __shared__ __attribute__((aligned(16))) _Float16 P16[16 * 64];    // 2048 B, persistent
  __shared__ float s_l[M2];
  __shared__ float den_w[64 * 8];
  __shared__ float dia[64];

  const int tid  = threadIdx.x;
  const int lane = tid & 63;
  const int wv   = tid >> 6;
  const int l15  = lane & 15;
  const int g    = lane >> 4;
  const int bh   = blockIdx.x >> 3;
  const int ch   = blockIdx.x & 7;

  const float* Qb = Qg + (size_t)bh * (N_TOK * DDIM) + (size_t)ch * 512 * DDIM;
  float*       Ob = Og + (size_t)bh * (N_TOK * DDIM) + (size_t)ch * 512 * DDIM;

  // ---- stage P (f16 [272][64]) into q' region + tile16 copy ----
  _Float16* Pl = (_Float16*)qp;
  for (int slot = tid; slot < (M2 * DDIM) / 8; slot += 512) {
    int m = slot >> 3, d0 = (slot & 7) * 8;
    h8 v;
    if (m < MFEAT) {
      float4 a = *(const float4*)(Pg + m * DDIM + d0);
      float4 b = *(const float4*)(Pg + m * DDIM + d0 + 4);
      v[0] = (_Float16)a.x; v[1] = (_Float16)a.y; v[2] = (_Float16)a.z; v[3] = (_Float16)a.w;
      v[4] = (_Float16)b.x; v[5] = (_Float16)b.y; v[6] = (_Float16)b.z; v[7] = (_Float16)b.w;
    } else {
      #pragma unroll
      for (int j = 0; j < 8; ++j) v[j] = (_Float16)0.0f;
    }
    *(h8*)(Pl + slot * 8) = v;
    if (m >= 256) *(h8*)(P16 + (m - 256) * DDIM + d0) = v;
  }
  __syncthreads();

  h8 pf[2][2];
  #pragma unroll
  for (int i = 0; i < 2; ++i) {
    int m = (wv + 8 * i) * 16 + l15;
    #pragma unroll
    for (int km = 0; km < 2; ++km)
      pf[i][km] = *(const h8*)(Pl + m * DDIM + km * 32 + 8 * g);
  }
  h8 pf16[2];
  #pragma unroll
  for (int km = 0; km < 2; ++km)
    pf16[km] = *(const h8*)(P16 + l15 * DDIM + km * 32 + 8 * g);
  __syncthreads();  // P region now reusable

  // ---- stage ctx^T into qp as [64][296] bf16 (coalesced) + s_l ----
  const float* cbp = ctxg + (size_t)bh * (M2 * DDIM);
  for (int slot = tid; slot < M2 * DDIM; slot += 512) {
    int m = slot >> 6, e = slot & 63;
    qp[e * QSTR + m] = f2bf(cbp[slot]);
  }
  for (int idx = tid; idx < 64 * 24; idx += 512) {     // zero ctxT pad cols 272..295
    int e = idx / 24, m = 272 + idx % 24;
    qp[e * QSTR + m] = 0;
  }
  for (int m = tid; m < M2; m += 512) s_l[m] = sveca[bh * M2 + m];
  __syncthreads();

  // ---- ctx fragments -> registers (wave's e-tile = wv&3) ----
  const int et = wv & 3, nh = wv >> 2;
  s8v cf[9];
  #pragma unroll
  for (int ks = 0; ks < 9; ++ks)
    cf[ks] = *(const s8v*)((const char*)(qp + (et * 16 + l15) * QSTR) + ks * 64 + 16 * g);
  __syncthreads();

  // ---- zero q' stale pad cols 272..287 (never rewritten) ----
  for (int idx = tid; idx < 64 * 16; idx += 512) {
    int rr = idx >> 4, cc = 272 + (idx & 15);
    qp[rr * QSTR + cc] = 0;
  }

  const f32x4 z4 = {0.f, 0.f, 0.f, 0.f};
  const int r  = tid >> 3;
  const int c8 = tid & 7;
  const int d0 = c8 * 8;
  h8 qv8; float ssq;

#define QS_LD(T)                                                              \
  {                                                                           \
    const float* qr_ = Qb + ((size_t)(T) * 64 + r) * DDIM + d0;               \
    float4 a_ = *(const float4*)qr_;                                          \
    float4 b_ = *(const float4*)(qr_ + 4);                                    \
    float ss_ = a_.x*a_.x + a_.y*a_.y + a_.z*a_.z + a_.w*a_.w                 \
              + b_.x*b_.x + b_.y*b_.y + b_.z*b_.z + b_.w*b_.w;                \
    ss_ += __shfl_xor(ss_, 1); ss_ += __shfl_xor(ss_, 2);                     \
    ss_ += __shfl_xor(ss_, 4);                                                \
    ssq = 0.5f * ss_;                                                         \
    qv8[0] = (_Float16)a_.x; qv8[1] = (_Float16)a_.y;                         \
    qv8[2] = (_Float16)a_.z; qv8[3] = (_Float16)a_.w;                         \
    qv8[4] = (_Float16)b_.x; qv8[5] = (_Float16)b_.y;                         \
    qv8[6] = (_Float16)b_.z; qv8[7] = (_Float16)b_.w;                         \
  }

#define QS_WR()                                                               \
  {                                                                           \
    if (c8 == 0) dia[r] = ssq;                                                \
    *(h8*)((char*)ql + r * 128 + ((16 * c8) ^ ((r & 7) << 4))) = qv8;         \
  }

  QS_LD(0);
  for (int it = 0; it < 8; ++it) {
    QS_WR();
    __syncthreads();   // ql/dia ready; also fences q'/den_w WAR vs prev out
    if (it + 1 < 8) QS_LD(it + 1);

    // ---- features: S = Q.P^T, exp, q' column writes, den partials ----
    #pragma unroll
    for (int nt = 0; nt < 4; ++nt) {
      int n = nt * 16 + l15;
      const char* arow = (const char*)ql + n * 128;
      int swn = (n & 7) << 4;
      h8 a0 = ldh8(arow, 16 * g, swn);
      h8 a1 = ldh8(arow, 64 + 16 * g, swn);
      float dg0 = dia[nt * 16 + 4 * g + 0];
      float dg1 = dia[nt * 16 + 4 * g + 1];
      float dg2 = dia[nt * 16 + 4 * g + 2];
      float dg3 = dia[nt * 16 + 4 * g + 3];
      float dl0 = 0.f, dl1 = 0.f, dl2 = 0.f, dl3 = 0.f;
      #pragma unroll
      for (int i = 0; i < 2; ++i) {
        int m = (wv + 8 * i) * 16 + l15;              // m <= 255
        f32x4 sc = z4;
        sc = MFMA_F16(a0, pf[i][0], sc);
        sc = MFMA_F16(a1, pf[i][1], sc);
        float sm = s_l[m];
        float e0 = __expf(sc[0] - dg0) + EPS_K;
        float e1 = __expf(sc[1] - dg1) + EPS_K;
        float e2 = __expf(sc[2] - dg2) + EPS_K;
        float e3 = __expf(sc[3] - dg3) + EPS_K;
        short* qcol = qp + m;
        qcol[(nt * 16 + 4 * g + 0) * QSTR] = f2bf(e0);
        qcol[(nt * 16 + 4 * g + 1) * QSTR] = f2bf(e1);
        qcol[(nt * 16 + 4 * g + 2) * QSTR] = f2bf(e2);
        qcol[(nt * 16 + 4 * g + 3) * QSTR] = f2bf(e3);
        dl0 += e0 * sm; dl1 += e1 * sm; dl2 += e2 * sm; dl3 += e3 * sm;
      }
      if (wv == nt) {                                  // tile 16 (s_l=0 for m>=266)
        int m = 256 + l15;
        f32x4 sc = z4;
        sc = MFMA_F16(a0, pf16[0], sc);
        sc = MFMA_F16(a1, pf16[1], sc);
        float sm = s_l[m];
        float e0 = __expf(sc[0] - dg0) + EPS_K;
        float e1 = __expf(sc[1] - dg1) + EPS_K;
        float e2 = __expf(sc[2] - dg2) + EPS_K;
        float e3 = __expf(sc[3] - dg3) + EPS_K;
        short* qcol = qp + m;
        qcol[(nt * 16 + 4 * g + 0) * QSTR] = f2bf(e0);
        qcol[(nt * 16 + 4 * g + 1) * QSTR] = f2bf(e1);
        qcol[(nt * 16 + 4 * g + 2) * QSTR] = f2bf(e2);
        qcol[(nt * 16 + 4 * g + 3) * QSTR] = f2bf(e3);
        dl0 += e0 * sm; dl1 += e1 * sm; dl2 += e2 * sm; dl3 += e3 * sm;
      }
      dl0 += __shfl_xor(dl0, 1); dl0 += __shfl_xor(dl0, 2); dl0 += __shfl_xor(dl0, 4); dl0 += __shfl_xor(dl0, 8);
      dl1 += __shfl_xor(dl1, 1); dl1 += __shfl_xor(dl1, 2); dl1 += __shfl_xor(dl1, 4); dl1 += __shfl_xor(dl1, 8);
      dl2 += __shfl_xor(dl2, 1); dl2 += __shfl_xor(dl2, 2); dl2 += __shfl_xor(dl2, 4); dl2 += __shfl_xor(dl2, 8);
      dl3 += __shfl_xor(dl3, 1); dl3 += __shfl_xor(dl3, 2); dl3 += __shfl_xor(dl3, 4); dl3 += __shfl_xor(dl3, 8);
      if (l15 == 0) {
        den_w[(nt * 16 + 4 * g + 0) * 8 + wv] = dl0;
        den_w[(nt * 16 + 4 * g + 1) * 8 + wv] = dl1;
        den_w[(nt * 16 + 4 * g + 2) * 8 + wv] = dl2;
        den_w[(nt * 16 + 4 * g + 3) * 8 + wv] = dl3;
      }
    }
    __syncthreads();

    // ---- out: wave (et, nh) computes 2 n-tiles x 1 e-tile ----
    #pragma unroll
    for (int nt2 = 0; nt2 < 2; ++nt2) {
      int nt = nh * 2 + nt2;
      const char* arow = (const char*)(qp + (nt * 16 + l15) * QSTR);
      f32x4 o = z4;
      #pragma unroll
      for (int ks = 0; ks < 9; ++ks) {
        s8v A = *(const s8v*)(arow + ks * 64 + 16 * g);
        o = MFMA_BF16(A, cf[ks], o);
      }
      #pragma unroll
      for (int rr = 0; rr < 4; ++rr) {
        int n = nt * 16 + 4 * g + rr;
        const f32x4* dq = (const f32x4*)(den_w + n * 8);
        f32x4 x = dq[0], y = dq[1];
        float s = ((x[0] + x[1]) + (x[2] + x[3])) + ((y[0] + y[1]) + (y[2] + y[3]));
        float dv = __builtin_amdgcn_rcpf(s);
        Ob[((size_t)it * 64 + n) * DDIM + et * 16 + l15] = o[rr] * dv;
      }
    }
  }
}

// ---------------------------------------------------------------------------
extern "C" void kernel_launch(void* const* d_in, const int* in_sizes, int n_in,
                              void* d_out, int out_size, void* d_ws, size_t ws_size,
                              hipStream_t stream)
{
  const float* q = (const float*)d_in[0];
  const float* k = (const float*)d_in[1];
  const float* v = (const float*)d_in[2];
  const float* p = (const float*)d_in[3];
  float* out = (float*)d_out;
  (void)in_sizes; (void)n_in; (void)out_size;

  // ws: [part_ctx BH*nch*272*64][part_s BH*nch*272][ctx BH*272*64][s BH*272] (fp32)
  int nch = 8;
  while (nch > 1) {
    size_t need = (size_t)4 * ((size_t)BHCNT * nch * (M2 * DDIM) + (size_t)BHCNT * nch * M2
                               + (size_t)BHCNT * (M2 * DDIM) + (size_t)BHCNT * M2);
    if (need <= ws_size) break;
    nch >>= 1;
  }
  float* part_ctx = (float*)d_ws;
  float* part_s   = part_ctx + (size_t)BHCNT * nch * (M2 * DDIM);
  float* ctxg     = part_s   + (size_t)BHCNT * nch * M2;
  float* sveca    = ctxg     + (size_t)BHCNT * (M2 * DDIM);

  perf_kside<<<dim3(BHCNT * nch), dim3(512), 0, stream>>>(k, v, p, part_ctx, part_s,
                                                          nch, N_TOK / nch);
  int redn = (BHCNT * M2 * DDIM + BHCNT * M2 + 255) / 256;
  perf_reduce<<<dim3(redn), dim3(256), 0, stream>>>(part_ctx, part_s, ctxg, sveca, nch);
  perf_qside<<<dim3(BHCNT * 8), dim3(512), 0, stream>>>(q, p, ctxg, sveca, out);
}